// Round 7
// baseline (230.122 us; speedup 1.0000x reference)
//
#include <hip/hip_runtime.h>
#include <stdint.h>

#define NB   8192
#define DIN  512
#define NH1  4096
#define NH2  4096
#define NA   64

typedef int v4i __attribute__((ext_vector_type(4)));

__device__ __forceinline__ v4i mfma_i8(v4i a, v4i b, v4i c) {
    return __builtin_amdgcn_mfma_i32_16x16x64_i8(a, b, c, 0, 0, 0);
}

// ---- async global->LDS, 16B per lane (dest = wave-uniform base + lane*16) ----
__device__ __forceinline__ void gload16(const void* g, const void* l) {
    __builtin_amdgcn_global_load_lds(
        (const __attribute__((address_space(1))) void*)(uintptr_t)g,
        (__attribute__((address_space(3))) void*)(uint32_t)(uintptr_t)l,
        16, 0, 0);
}

// ---------------- converts ----------------
__global__ void cvt_i8(const float* __restrict__ in, signed char* __restrict__ out, int n4) {
    const int i = blockIdx.x * blockDim.x + threadIdx.x;
    if (i >= n4) return;
    const float4 v = ((const float4*)in)[i];
    char4 c;
    c.x = (signed char)__float2int_rn(v.x);
    c.y = (signed char)__float2int_rn(v.y);
    c.z = (signed char)__float2int_rn(v.z);
    c.w = (signed char)__float2int_rn(v.w);
    ((char4*)out)[i] = c;
}

// S[a] = sum_k round(wp[a][k])
__global__ void sum_wp(const float* __restrict__ wp, int* __restrict__ S) {
    __shared__ int red[256];
    const int a = blockIdx.x, t = threadIdx.x;
    int p = 0;
    for (int k = t; k < NH2; k += 256) p += __float2int_rn(wp[(size_t)a * NH2 + k]);
    red[t] = p; __syncthreads();
    for (int s = 128; s > 0; s >>= 1) { if (t < s) red[t] += red[t + s]; __syncthreads(); }
    if (t == 0) S[a] = red[0];
}

// ---------------- i8 GEMM, C = A(MxK) * B(NxK)^T ----------------
// 256x128 tile, BK=64, 8 waves (4Mx2N, wave tile 64x64), 3-buffer LDS (72KB),
// 2 blocks/CU (16 waves/CU). Fragment READ-AHEAD: tile t+1's ds_reads are
// WAR-pinned inside tile t's MFMA cluster (LDS pipe runs under MFMA pipe).
// ONE barrier per K-tile; counted vmcnt(3) never drains in steady state.
// EPI=1: h1q = clip(round(relu(round(M*acc+b))/s), -128,127) i8 -> out0
// EPI=2: rr  = relu(round(M*(acc+b))); out0 = (rr&255)-128, out1 = (rr>>8)-128
template <int EPI>
__global__ __launch_bounds__(512, 4)
void gemm_ra(const signed char* __restrict__ Ag,
             const signed char* __restrict__ Bg,
             int M, int N, int K,
             const float* __restrict__ bias,
             const float* __restrict__ Mscale,
             const float* __restrict__ qscale,
             signed char* __restrict__ out0,
             signed char* __restrict__ out1)
{
    // buf: [A 256x64 : 16384 | B 128x64 : 8192] = 24KB, x3 buffers = 72KB
    __shared__ __align__(16) signed char lds[3][24576];

    const int tid  = threadIdx.x;
    const int lane = tid & 63;
    const int wid  = tid >> 6;
    const int wm   = wid >> 1, wn = wid & 1;   // 4x2 waves, wave tile 64x64

    // XCD-aware bijective swizzle (grid divisible by 8), N-fastest
    const int nwg  = gridDim.x;
    const int bid  = blockIdx.x;
    const int swzb = (bid & 7) * (nwg >> 3) + (bid >> 3);
    const int nbx  = N >> 7;
    const int bx   = swzb % nbx;
    const int by   = swzb / nbx;
    const int bm0  = by << 8, bn0 = bx << 7;

    // staging: thread t -> slab row t>>2, phys chunk t&3, logical (t&3)^((t>>3)&3)
    const int srow = tid >> 2;
    const int sc   = (((tid & 3) ^ ((tid >> 3) & 3)) << 4);
    const signed char* aS = Ag + (size_t)(bm0 + srow) * K + sc;
    const signed char* bS = Bg + (size_t)(bn0 + srow) * K + sc;
    const size_t rK = (size_t)128 * K;   // 128-row slab stride

#define STG(bp, t) do { \
    const int ko_ = (t) << 6; \
    gload16(aS + ko_,      &lds[bp][0]     + tid * 16); \
    gload16(aS + rK + ko_, &lds[bp][8192]  + tid * 16); \
    gload16(bS + ko_,      &lds[bp][16384] + tid * 16); } while (0)

    // ds_read: lane -> frag row base + (lane&15), logical k-chunk lane>>4
    const int r    = lane & 15;
    const int pc   = (((lane >> 4) ^ ((r >> 1) & 3)) << 4);
    const int aoff = wm * 4096 + r * 64 + pc;           // + m*1024, m=0..3
    const int boff = 16384 + wn * 4096 + r * 64 + pc;   // + n*1024, n=0..3

    const int nt = K >> 6;

    // prologue: stage t0,t1; wait t0 (t1 in flight); preload tile-0 fragments
    STG(0, 0);
    STG(1, 1);
    asm volatile("s_waitcnt vmcnt(3)" ::: "memory");
    __builtin_amdgcn_s_barrier();

    v4i af[4], bf[4];
    {
        const signed char* L = &lds[0][0];
        #pragma unroll
        for (int m = 0; m < 4; ++m) af[m] = *(const v4i*)(L + aoff + m * 1024);
        #pragma unroll
        for (int n = 0; n < 4; ++n) bf[n] = *(const v4i*)(L + boff + n * 1024);
    }

    v4i acc[4][4] = {};
    int cur = 0;

    for (int t = 0; t < nt; ++t) {
        // stage t+2 into buf[(t+2)%3] (last read 2 barriers ago -> safe),
        // then ensure t+1's loads landed (leave t+2's 3 in flight).
        if (t + 2 < nt) {
            const int nb = (cur == 0) ? 2 : cur - 1;   // (t+2)%3
            STG(nb, t + 2);
            asm volatile("s_waitcnt vmcnt(3)" ::: "memory");
        } else {
            asm volatile("s_waitcnt vmcnt(0)" ::: "memory");
        }
        __builtin_amdgcn_s_barrier();   // ONLY barrier per K-tile

        const int nxt = (cur == 2) ? 0 : cur + 1;
        const signed char* Ln = &lds[nxt][0];   // stale at t=nt-1 (reads unused)

        // MFMA(t) with tile-(t+1) fragment reads WAR-pinned after last use
        __builtin_amdgcn_s_setprio(1);
        #pragma unroll
        for (int m = 0; m < 4; ++m) {
            #pragma unroll
            for (int n = 0; n < 4; ++n)
                acc[m][n] = mfma_i8(af[m], bf[n], acc[m][n]);
            af[m] = *(const v4i*)(Ln + aoff + m * 1024);
        }
        __builtin_amdgcn_s_setprio(0);
        #pragma unroll
        for (int n = 0; n < 4; ++n) bf[n] = *(const v4i*)(Ln + boff + n * 1024);

        cur = nxt;
    }
#undef STG

    // ---- epilogue (round-3 verified, 0 conflicts): img [256][136], int2 flush ----
    __syncthreads();   // drains lgkm/vmcnt; stale frag reads complete (unused)
    signed char* img0 = (signed char*)&lds[0][0];
    signed char* img1 = img0 + 34816;            // 2 x 34816 = 69632 <= 73728
    const int rowb = wm * 64 + ((lane >> 4) << 2);
    const int colb = wn * 64 + (lane & 15);

#define FLUSH(dst, img) do { \
    _Pragma("unroll") \
    for (int p = 0; p < 8; ++p) { \
        const int idx = p * 512 + tid; \
        const int row = idx >> 4; \
        const int cb  = (idx & 15) * 8; \
        *(int2*)((dst) + (size_t)(bm0 + row) * N + bn0 + cb) = \
            *(const int2*)((img) + row * 136 + cb); \
    } } while (0)

    if constexpr (EPI == 1) {
        const float Mv = Mscale[0];
        const float sv = qscale[0];
        #pragma unroll
        for (int n = 0; n < 4; ++n) {
            const int col  = colb + n * 16;
            const int bint = __float2int_rn(bias[bn0 + col]);
            #pragma unroll
            for (int m = 0; m < 4; ++m) {
                #pragma unroll
                for (int j = 0; j < 4; ++j) {
                    const int row  = rowb + m * 16 + j;
                    const int accv = acc[m][n][j] + bint;      // |acc1| <= 8.4M: f32-exact
                    float h = rintf(Mv * (float)accv);
                    h = fmaxf(h, 0.0f);
                    float q = rintf(h / sv);
                    q = fminf(fmaxf(q, -128.0f), 127.0f);
                    img0[row * 136 + col] = (signed char)(int)q;
                }
            }
        }
        __syncthreads();
        FLUSH(out0, img0);
    } else {
        const float Mv = Mscale[0];
        #pragma unroll
        for (int n = 0; n < 4; ++n) {
            const int col  = colb + n * 16;
            const int bint = __float2int_rn(bias[bn0 + col]);
            #pragma unroll
            for (int m = 0; m < 4; ++m) {
                #pragma unroll
                for (int j = 0; j < 4; ++j) {
                    const int row  = rowb + m * 16 + j;
                    const int accv = acc[m][n][j] + bint;      // |acc2| <= 66.6M: f64 exact
                    double rr = rint((double)Mv * (double)accv);
                    rr = rr > 0.0 ? rr : 0.0;                  // relu; <= 65024
                    const int v = (int)rr;
                    img0[row * 136 + col] = (signed char)((v & 255) - 128);
                    img1[row * 136 + col] = (signed char)((v >> 8) - 128);
                }
            }
        }
        __syncthreads();
        FLUSH(out0, img0);
        FLUSH(out1, img1);
    }
#undef FLUSH
}

// ---------------- head MFMA: partial[kblk][r][a] = 256*Phi + Plo over K-chunk 512 ----------------
__global__ __launch_bounds__(512, 1)
void head_mfma(const signed char* __restrict__ lo,
               const signed char* __restrict__ hi,
               const signed char* __restrict__ wpq,
               int* __restrict__ part)
{
    __shared__ __align__(16) signed char Bl[32768];       // 64 x 512 i8 (swizzled)
    __shared__ __align__(16) signed char Al[3][32768];    // [lo 256x64 | hi 256x64]

    const int tid  = threadIdx.x;
    const int lane = tid & 63;
    const int wid  = tid >> 6;
    const int rblk = blockIdx.x >> 3;
    const int kblk = blockIdx.x & 7;
    const int bm0  = rblk << 8;
    const int kb   = kblk << 9;

    #pragma unroll
    for (int s = 0; s < 4; ++s) {
        const int brow = s * 16 + (tid >> 5);
        const int pch  = tid & 31;
        const int lc   = pch ^ (brow & 7);
        gload16(wpq + (size_t)brow * NH2 + kb + lc * 16, Bl + brow * 512 + pch * 16);
    }

    const int srow  = tid >> 2;
    const int sclog = (tid & 3) ^ ((tid >> 3) & 3);
    const size_t ab = (size_t)(bm0 + srow) * NH2 + kb + sclog * 16;
    const size_t rK = (size_t)128 * NH2;

    #define HSTAGE(bp, ko) do { \
        gload16(lo + ab + (ko),      &Al[bp][0]     + tid * 16); \
        gload16(lo + ab + rK + (ko), &Al[bp][8192]  + tid * 16); \
        gload16(hi + ab + (ko),      &Al[bp][16384] + tid * 16); \
        gload16(hi + ab + rK + (ko), &Al[bp][24576] + tid * 16); } while (0)

    HSTAGE(0, 0);
    HSTAGE(1, 64);

    const int r    = lane & 15;
    const int cg   = lane >> 4;
    const int pcA  = (cg ^ ((r >> 1) & 3)) * 16;
    const int aoff = wid * 2048 + r * 64 + pcA;

    v4i accL[2][4] = {}, accH[2][4] = {};
    int cur = 0, nxt = 2;

    for (int t = 0; t < 8; ++t) {
        if (t < 7) asm volatile("s_waitcnt vmcnt(4)" ::: "memory");
        else       asm volatile("s_waitcnt vmcnt(0)" ::: "memory");
        __builtin_amdgcn_s_barrier();

        const signed char* A = &Al[cur][0];
        v4i bf[4], al[2], ah[2];
        #pragma unroll
        for (int n = 0; n < 4; ++n)
            bf[n] = *(const v4i*)(Bl + (n * 16 + r) * 512 + (((t * 4 + cg) ^ (r & 7)) * 16));
        #pragma unroll
        for (int m = 0; m < 2; ++m) al[m] = *(const v4i*)(A + aoff + m * 1024);
        #pragma unroll
        for (int m = 0; m < 2; ++m) ah[m] = *(const v4i*)(A + 16384 + aoff + m * 1024);

        if (t + 2 < 8) HSTAGE(nxt, (t + 2) << 6);

        __builtin_amdgcn_s_setprio(1);
        #pragma unroll
        for (int m = 0; m < 2; ++m)
            #pragma unroll
            for (int n = 0; n < 4; ++n) {
                accL[m][n] = mfma_i8(al[m], bf[n], accL[m][n]);
                accH[m][n] = mfma_i8(ah[m], bf[n], accH[m][n]);
            }
        __builtin_amdgcn_s_setprio(0);
        __builtin_amdgcn_s_barrier();

        cur = (cur == 2) ? 0 : cur + 1;
        nxt = (nxt == 2) ? 0 : nxt + 1;
    }
    #undef HSTAGE

    int* pb = part + (size_t)kblk * (NB * NA);
    const int rowb = bm0 + wid * 32 + ((lane >> 4) << 2);
    #pragma unroll
    for (int m = 0; m < 2; ++m)
        #pragma unroll
        for (int n = 0; n < 4; ++n) {
            const int a = n * 16 + (lane & 15);
            #pragma unroll
            for (int j = 0; j < 4; ++j) {
                const int row = rowb + m * 16 + j;
                pb[(size_t)row * NA + a] = accL[m][n][j] + (accH[m][n][j] << 8);
            }
        }
}

// ---------------- combine: out = round(Mp*(sum parts + 32896*S[a] + b[a])) ----------------
__global__ __launch_bounds__(256)
void comb_head(const int* __restrict__ part, const int* __restrict__ S,
               const float* __restrict__ bp, const float* __restrict__ Mp,
               float* __restrict__ out)
{
    const int t = blockIdx.x * 256 + threadIdx.x;   // 524288
    const int a = t & 63;
    long long sum = 0;
    #pragma unroll
    for (int c = 0; c < 8; ++c) sum += part[(size_t)c * (NB * NA) + t];
    sum += 32896LL * (long long)S[a] + (long long)__float2int_rn(bp[a]);
    out[t] = (float)rint((double)Mp[0] * (double)sum);
}

// ---------------- launcher ----------------
extern "C" void kernel_launch(void* const* d_in, const int* in_sizes, int n_in,
                              void* d_out, int out_size, void* d_ws, size_t ws_size,
                              hipStream_t stream) {
    const float* x  = (const float*)d_in[0];
    const float* w1 = (const float*)d_in[1];
    const float* b1 = (const float*)d_in[2];
    const float* w2 = (const float*)d_in[3];
    const float* b2 = (const float*)d_in[4];
    const float* wp = (const float*)d_in[7];
    const float* bp = (const float*)d_in[8];
    const float* M1 = (const float*)d_in[9];
    const float* M2 = (const float*)d_in[10];
    const float* Mp = (const float*)d_in[12];
    const float* s2 = (const float*)d_in[13];

    const size_t MB = (size_t)1 << 20;
    char* ws = (char*)d_ws;
    signed char* x_i8  = (signed char*)(ws);              // 4 MiB   (dead after GEMM1)
    signed char* w1_i8 = (signed char*)(ws + 4  * MB);    // 2 MiB   (dead after GEMM1)
    signed char* w2_i8 = (signed char*)(ws + 6  * MB);    // 16 MiB  (dead after GEMM2)
    signed char* wp_i8 = (signed char*)(ws + 22 * MB);    // 256 KiB
    int*         Ssum  = (int*)        (ws + 22 * MB + 512 * 1024); // 256 B
    signed char* h1q   = (signed char*)(ws + 23 * MB);    // 32 MiB
    signed char* h2lo  = (signed char*)(ws + 55 * MB);    // 32 MiB
    signed char* h2hi  = (signed char*)(ws + 87 * MB);    // 32 MiB
    int*         part  = (int*)        (ws);              // 16 MiB, overlays x/w1/w2 (used only after GEMM2)

    cvt_i8<<<dim3(4096),  dim3(256), 0, stream>>>(x,  x_i8,  NB  * DIN / 4);
    cvt_i8<<<dim3(2048),  dim3(256), 0, stream>>>(w1, w1_i8, NH1 * DIN / 4);
    cvt_i8<<<dim3(16384), dim3(256), 0, stream>>>(w2, w2_i8, NH2 * NH1 / 4);
    cvt_i8<<<dim3(256),   dim3(256), 0, stream>>>(wp, wp_i8, NA  * NH2 / 4);
    sum_wp<<<dim3(64), dim3(256), 0, stream>>>(wp, Ssum);

    // GEMM1: (8192x512) x (4096x512)^T -> h1q int8
    gemm_ra<1><<<dim3((NB / 256) * (NH1 / 128)), dim3(512), 0, stream>>>(
        x_i8, w1_i8, NB, NH1, DIN, b1, M1, s2, h1q, nullptr);
    // GEMM2: (8192x4096) x (4096x4096)^T -> h2lo/h2hi i8 planes
    gemm_ra<2><<<dim3((NB / 256) * (NH2 / 128)), dim3(512), 0, stream>>>(
        h1q, w2_i8, NB, NH2, NH1, b2, M2, nullptr, h2lo, h2hi);
    // head: 256 blocks (32 row-tiles x 8 K-chunks) -> part, then combine
    head_mfma<<<dim3(256), dim3(512), 0, stream>>>(h2lo, h2hi, wp_i8, part);
    comb_head<<<dim3(NB * NA / 256), dim3(256), 0, stream>>>(part, Ssum, bp, Mp, (float*)d_out);
}

// Round 8
// 208.811 us; speedup vs baseline: 1.1021x; 1.1021x over previous
//
#include <hip/hip_runtime.h>
#include <stdint.h>

#define NB   8192
#define DIN  512
#define NH1  4096
#define NH2  4096
#define NA   64

typedef int v4i __attribute__((ext_vector_type(4)));

__device__ __forceinline__ v4i mfma_i8(v4i a, v4i b, v4i c) {
    return __builtin_amdgcn_mfma_i32_16x16x64_i8(a, b, c, 0, 0, 0);
}

// ---- async global->LDS, 16B per lane (dest = wave-uniform base + lane*16) ----
__device__ __forceinline__ void gload16(const void* g, const void* l) {
    __builtin_amdgcn_global_load_lds(
        (const __attribute__((address_space(1))) void*)(uintptr_t)g,
        (__attribute__((address_space(3))) void*)(uint32_t)(uintptr_t)l,
        16, 0, 0);
}

// ---------------- converts ----------------
__global__ void cvt_i8(const float* __restrict__ in, signed char* __restrict__ out, int n4) {
    const int i = blockIdx.x * blockDim.x + threadIdx.x;
    if (i >= n4) return;
    const float4 v = ((const float4*)in)[i];
    char4 c;
    c.x = (signed char)__float2int_rn(v.x);
    c.y = (signed char)__float2int_rn(v.y);
    c.z = (signed char)__float2int_rn(v.z);
    c.w = (signed char)__float2int_rn(v.w);
    ((char4*)out)[i] = c;
}

// x (8192x512 f32) -> fragment layout: unit u=(g,kt,l): xf[u*16+b] = x[16g+(l&15)][64kt+(l>>4)*16+b]
__global__ void cvt_xfrag(const float* __restrict__ x, signed char* __restrict__ xf) {
    const int u   = blockIdx.x * 256 + threadIdx.x;   // 262144 units
    const int g   = u >> 9;            // 512 units per 16-row group (8 kt * 64 l)
    const int rem = u & 511;
    const int kt  = rem >> 6;
    const int l   = rem & 63;
    const int row = g * 16 + (l & 15);
    const int k0  = kt * 64 + (l >> 4) * 16;
    const float4* src = (const float4*)(x + (size_t)row * DIN + k0);
    signed char v[16];
    #pragma unroll
    for (int q = 0; q < 4; ++q) {
        const float4 f = src[q];
        v[q*4+0] = (signed char)__float2int_rn(f.x);
        v[q*4+1] = (signed char)__float2int_rn(f.y);
        v[q*4+2] = (signed char)__float2int_rn(f.z);
        v[q*4+3] = (signed char)__float2int_rn(f.w);
    }
    *(int4*)(xf + (size_t)u * 16) = *(const int4*)v;
}

// S[a] = sum_k round(wp[a][k])
__global__ void sum_wp(const float* __restrict__ wp, int* __restrict__ S) {
    __shared__ int red[256];
    const int a = blockIdx.x, t = threadIdx.x;
    int p = 0;
    for (int k = t; k < NH2; k += 256) p += __float2int_rn(wp[(size_t)a * NH2 + k]);
    red[t] = p; __syncthreads();
    for (int s = 128; s > 0; s >>= 1) { if (t < s) red[t] += red[t + s]; __syncthreads(); }
    if (t == 0) S[a] = red[0];
}

// ---------------- i8 GEMM, C = A(MxK,FRAGMENT layout) * B(NxK row-major)^T ----------------
// 256x128 tile, BK=64, 8 waves (4Mx2N, wave 64x64), 2 blocks/CU.
// A-fragments: global_load_dwordx4 direct from L2 (read-ahead 1 tile, WAR-pinned in cluster).
// B: 3-buffer LDS (8KB each) via gload_lds + XOR swizzle; counted vmcnt(1) never drains.
// EPI=1: h1q = clip(round(relu(round(M*acc+b))/s),-128,127) i8 -> out0 in FRAGMENT layout
// EPI=2: rr  = relu(round(M*(acc+b))); out0=(rr&255)-128, out1=(rr>>8)-128 (row-major planes)
template <int EPI>
__global__ __launch_bounds__(512, 4)
void gemm_af(const signed char* __restrict__ Af,
             const signed char* __restrict__ Bg,
             int M, int N, int K,
             const float* __restrict__ bias,
             const float* __restrict__ Mscale,
             const float* __restrict__ qscale,
             signed char* __restrict__ out0,
             signed char* __restrict__ out1)
{
    // [0,24KB): 3 x 8KB B buffers; epilogue reuses as img planes (2 x 34816 = 69632)
    __shared__ __align__(16) signed char lds[69632];

    const int tid  = threadIdx.x;
    const int lane = tid & 63;
    const int wid  = tid >> 6;
    const int wm   = wid >> 1, wn = wid & 1;   // 4M x 2N waves, 64x64 each

    // XCD-aware bijective swizzle (grid divisible by 8), N-fastest
    const int nwg  = gridDim.x;
    const int bid  = blockIdx.x;
    const int swzb = (bid & 7) * (nwg >> 3) + (bid >> 3);
    const int nbx  = N >> 7;
    const int bx   = swzb % nbx;
    const int by   = swzb / nbx;
    const int bm0  = by << 8, bn0 = bx << 7;

    // B staging: 512 thr x 16B = 8KB tile (128 rows x 64B); XOR chunk swizzle
    const int srow = tid >> 2;
    const int sc   = (((tid & 3) ^ ((tid >> 3) & 3)) << 4);
    const signed char* bS = Bg + (size_t)(bn0 + srow) * K + sc;

    // B frag ds_read: lane -> row (lane&15), logical k-chunk lane>>4
    const int r    = lane & 15;
    const int pc   = (((lane >> 4) ^ ((r >> 1) & 3)) << 4);
    const int boff = wn * 4096 + r * 64 + pc;   // + n*1024

    // A fragment base: g = (bm0>>4) + wm*4 + m ; addr = ((g*NKT + kt)<<10) + lane*16
    const int NKT = K >> 6;
    const signed char* afB = Af + (((size_t)((bm0 >> 4) + wm * 4) * NKT) << 10) + lane * 16;

    const int nt = K >> 6;

    // prologue: af(0) x4 loads, stage B(0), B(1); vmcnt(1) ensures af+B0 done, B1 in flight
    v4i af[4], bf[4];
    #pragma unroll
    for (int m = 0; m < 4; ++m)
        af[m] = *(const v4i*)(afB + (((size_t)(m * NKT)) << 10));
    gload16(bS,      lds + tid * 16);
    gload16(bS + 64, lds + 8192 + tid * 16);
    asm volatile("s_waitcnt vmcnt(1)" ::: "memory");
    __builtin_amdgcn_s_barrier();

    v4i acc[4][4] = {};

    for (int t = 0; t < nt; ++t) {
        const signed char* L = lds + (t % 3) * 8192;
        #pragma unroll
        for (int n = 0; n < 4; ++n) bf[n] = *(const v4i*)(L + boff + n * 1024);

        const size_t tl = (size_t)((t + 1 < nt) ? (t + 1) : t);   // clamped read-ahead

        __builtin_amdgcn_s_setprio(1);
        #pragma unroll
        for (int m = 0; m < 4; ++m) {
            #pragma unroll
            for (int n = 0; n < 4; ++n)
                acc[m][n] = mfma_i8(af[m], bf[n], acc[m][n]);
            af[m] = *(const v4i*)(afB + (((size_t)(m * NKT) + tl) << 10));  // af(t+1), WAR-pinned
        }
        __builtin_amdgcn_s_setprio(0);

        if (t + 2 < nt) {
            gload16(bS + ((t + 2) << 6), lds + ((t + 2) % 3) * 8192 + tid * 16);
            // outstanding oldest->newest: B(t+1), af(t+1)x4, B(t+2) -> drain all but B(t+2)
            asm volatile("s_waitcnt vmcnt(1)" ::: "memory");
        } else if (t + 1 < nt) {
            asm volatile("s_waitcnt vmcnt(0)" ::: "memory");
        }
        __builtin_amdgcn_s_barrier();
    }

    // ---- epilogue: LDS img [256][136] per plane ----
    __syncthreads();
    signed char* img0 = lds;
    signed char* img1 = lds + 34816;
    const int rowb = wm * 64 + ((lane >> 4) << 2);
    const int colb = wn * 64 + (lane & 15);

    if constexpr (EPI == 1) {
        const float Mv = Mscale[0];
        const float sv = qscale[0];
        #pragma unroll
        for (int n = 0; n < 4; ++n) {
            const int col  = colb + n * 16;
            const int bint = __float2int_rn(bias[bn0 + col]);
            #pragma unroll
            for (int m = 0; m < 4; ++m) {
                #pragma unroll
                for (int j = 0; j < 4; ++j) {
                    const int row  = rowb + m * 16 + j;
                    const int accv = acc[m][n][j] + bint;      // |acc1| <= 8.4M: f32-exact
                    float h = rintf(Mv * (float)accv);
                    h = fmaxf(h, 0.0f);
                    float q = rintf(h / sv);
                    q = fminf(fmaxf(q, -128.0f), 127.0f);
                    img0[row * 136 + col] = (signed char)(int)q;
                }
            }
        }
        __syncthreads();
        // flush to FRAGMENT layout: unit (g, kt, l) <- img[g_l*16+(l&15)][kt_l*64+(l>>4)*16]
        const int oNKT = N >> 6;
        #pragma unroll
        for (int i = 0; i < 4; ++i) {
            const int u    = i * 512 + tid;        // 2048 units x 16B = 32KB
            const int g_l  = u >> 7;
            const int kt_l = (u >> 6) & 1;
            const int l    = u & 63;
            const int lrow = g_l * 16 + (l & 15);
            const int lcol = kt_l * 64 + (l >> 4) * 16;
            const size_t g  = (size_t)((bm0 >> 4) + g_l);
            const size_t kt = (size_t)((bn0 >> 6) + kt_l);
            *(int4*)(out0 + ((g * oNKT + kt) << 10) + l * 16) =
                *(const int4*)(img0 + lrow * 136 + lcol);
        }
    } else {
        const float Mv = Mscale[0];
        #pragma unroll
        for (int n = 0; n < 4; ++n) {
            const int col  = colb + n * 16;
            const int bint = __float2int_rn(bias[bn0 + col]);
            #pragma unroll
            for (int m = 0; m < 4; ++m) {
                #pragma unroll
                for (int j = 0; j < 4; ++j) {
                    const int row  = rowb + m * 16 + j;
                    const int accv = acc[m][n][j] + bint;      // |acc2| <= 66.6M: f64 exact
                    double rr = rint((double)Mv * (double)accv);
                    rr = rr > 0.0 ? rr : 0.0;                  // relu; <= 65024
                    const int v = (int)rr;
                    img0[row * 136 + col] = (signed char)((v & 255) - 128);
                    img1[row * 136 + col] = (signed char)((v >> 8) - 128);
                }
            }
        }
        __syncthreads();
        #pragma unroll
        for (int p = 0; p < 8; ++p) {
            const int idx = p * 512 + tid;
            const int row = idx >> 4;
            const int cb  = (idx & 15) * 8;
            const size_t gaddr = (size_t)(bm0 + row) * N + bn0 + cb;
            *(int2*)(out0 + gaddr) = *(const int2*)(img0 + row * 136 + cb);
            *(int2*)(out1 + gaddr) = *(const int2*)(img1 + row * 136 + cb);
        }
    }
}

// ---------------- head MFMA: partial[kblk][r][a] = 256*Phi + Plo over K-chunk 512 ----------------
__global__ __launch_bounds__(512, 1)
void head_mfma(const signed char* __restrict__ lo,
               const signed char* __restrict__ hi,
               const signed char* __restrict__ wpq,
               int* __restrict__ part)
{
    __shared__ __align__(16) signed char Bl[32768];       // 64 x 512 i8 (swizzled)
    __shared__ __align__(16) signed char Al[3][32768];    // [lo 256x64 | hi 256x64]

    const int tid  = threadIdx.x;
    const int lane = tid & 63;
    const int wid  = tid >> 6;
    const int rblk = blockIdx.x >> 3;
    const int kblk = blockIdx.x & 7;
    const int bm0  = rblk << 8;
    const int kb   = kblk << 9;

    #pragma unroll
    for (int s = 0; s < 4; ++s) {
        const int brow = s * 16 + (tid >> 5);
        const int pch  = tid & 31;
        const int lc   = pch ^ (brow & 7);
        gload16(wpq + (size_t)brow * NH2 + kb + lc * 16, Bl + brow * 512 + pch * 16);
    }

    const int srow  = tid >> 2;
    const int sclog = (tid & 3) ^ ((tid >> 3) & 3);
    const size_t ab = (size_t)(bm0 + srow) * NH2 + kb + sclog * 16;
    const size_t rK = (size_t)128 * NH2;

    #define HSTAGE(bp, ko) do { \
        gload16(lo + ab + (ko),      &Al[bp][0]     + tid * 16); \
        gload16(lo + ab + rK + (ko), &Al[bp][8192]  + tid * 16); \
        gload16(hi + ab + (ko),      &Al[bp][16384] + tid * 16); \
        gload16(hi + ab + rK + (ko), &Al[bp][24576] + tid * 16); } while (0)

    HSTAGE(0, 0);
    HSTAGE(1, 64);

    const int r    = lane & 15;
    const int cg   = lane >> 4;
    const int pcA  = (cg ^ ((r >> 1) & 3)) * 16;
    const int aoff = wid * 2048 + r * 64 + pcA;

    v4i accL[2][4] = {}, accH[2][4] = {};
    int cur = 0, nxt = 2;

    for (int t = 0; t < 8; ++t) {
        if (t < 7) asm volatile("s_waitcnt vmcnt(4)" ::: "memory");
        else       asm volatile("s_waitcnt vmcnt(0)" ::: "memory");
        __builtin_amdgcn_s_barrier();

        const signed char* A = &Al[cur][0];
        v4i bf[4], al[2], ah[2];
        #pragma unroll
        for (int n = 0; n < 4; ++n)
            bf[n] = *(const v4i*)(Bl + (n * 16 + r) * 512 + (((t * 4 + cg) ^ (r & 7)) * 16));
        #pragma unroll
        for (int m = 0; m < 2; ++m) al[m] = *(const v4i*)(A + aoff + m * 1024);
        #pragma unroll
        for (int m = 0; m < 2; ++m) ah[m] = *(const v4i*)(A + 16384 + aoff + m * 1024);

        if (t + 2 < 8) HSTAGE(nxt, (t + 2) << 6);

        __builtin_amdgcn_s_setprio(1);
        #pragma unroll
        for (int m = 0; m < 2; ++m)
            #pragma unroll
            for (int n = 0; n < 4; ++n) {
                accL[m][n] = mfma_i8(al[m], bf[n], accL[m][n]);
                accH[m][n] = mfma_i8(ah[m], bf[n], accH[m][n]);
            }
        __builtin_amdgcn_s_setprio(0);
        __builtin_amdgcn_s_barrier();

        cur = (cur == 2) ? 0 : cur + 1;
        nxt = (nxt == 2) ? 0 : nxt + 1;
    }
    #undef HSTAGE

    int* pb = part + (size_t)kblk * (NB * NA);
    const int rowb = bm0 + wid * 32 + ((lane >> 4) << 2);
    #pragma unroll
    for (int m = 0; m < 2; ++m)
        #pragma unroll
        for (int n = 0; n < 4; ++n) {
            const int a = n * 16 + (lane & 15);
            #pragma unroll
            for (int j = 0; j < 4; ++j) {
                const int row = rowb + m * 16 + j;
                pb[(size_t)row * NA + a] = accL[m][n][j] + (accH[m][n][j] << 8);
            }
        }
}

// ---------------- combine: out = round(Mp*(sum parts + 32896*S[a] + b[a])) ----------------
__global__ __launch_bounds__(256)
void comb_head(const int* __restrict__ part, const int* __restrict__ S,
               const float* __restrict__ bp, const float* __restrict__ Mp,
               float* __restrict__ out)
{
    const int t = blockIdx.x * 256 + threadIdx.x;   // 524288
    const int a = t & 63;
    long long sum = 0;
    #pragma unroll
    for (int c = 0; c < 8; ++c) sum += part[(size_t)c * (NB * NA) + t];
    sum += 32896LL * (long long)S[a] + (long long)__float2int_rn(bp[a]);
    out[t] = (float)rint((double)Mp[0] * (double)sum);
}

// ---------------- launcher ----------------
extern "C" void kernel_launch(void* const* d_in, const int* in_sizes, int n_in,
                              void* d_out, int out_size, void* d_ws, size_t ws_size,
                              hipStream_t stream) {
    const float* x  = (const float*)d_in[0];
    const float* w1 = (const float*)d_in[1];
    const float* b1 = (const float*)d_in[2];
    const float* w2 = (const float*)d_in[3];
    const float* b2 = (const float*)d_in[4];
    const float* wp = (const float*)d_in[7];
    const float* bp = (const float*)d_in[8];
    const float* M1 = (const float*)d_in[9];
    const float* M2 = (const float*)d_in[10];
    const float* Mp = (const float*)d_in[12];
    const float* s2 = (const float*)d_in[13];

    const size_t MB = (size_t)1 << 20;
    char* ws = (char*)d_ws;
    signed char* xf    = (signed char*)(ws);              // 4 MiB   x in fragment layout
    signed char* w1_i8 = (signed char*)(ws + 4  * MB);    // 2 MiB
    signed char* w2_i8 = (signed char*)(ws + 6  * MB);    // 16 MiB
    signed char* wp_i8 = (signed char*)(ws + 22 * MB);    // 256 KiB
    int*         Ssum  = (int*)        (ws + 22 * MB + 512 * 1024); // 256 B
    signed char* h1f   = (signed char*)(ws + 23 * MB);    // 32 MiB  h1q in fragment layout
    signed char* h2lo  = (signed char*)(ws + 55 * MB);    // 32 MiB
    signed char* h2hi  = (signed char*)(ws + 87 * MB);    // 32 MiB
    int*         part  = (int*)        (ws);              // 16 MiB, overlays xf/w1/w2 (post-GEMM2)

    cvt_xfrag<<<dim3(1024), dim3(256), 0, stream>>>(x, xf);
    cvt_i8<<<dim3(2048),  dim3(256), 0, stream>>>(w1, w1_i8, NH1 * DIN / 4);
    cvt_i8<<<dim3(16384), dim3(256), 0, stream>>>(w2, w2_i8, NH2 * NH1 / 4);
    cvt_i8<<<dim3(256),   dim3(256), 0, stream>>>(wp, wp_i8, NA  * NH2 / 4);
    sum_wp<<<dim3(64), dim3(256), 0, stream>>>(wp, Ssum);

    // GEMM1: (8192x512 frag) x (4096x512)^T -> h1f (fragment layout)
    gemm_af<1><<<dim3((NB / 256) * (NH1 / 128)), dim3(512), 0, stream>>>(
        xf, w1_i8, NB, NH1, DIN, b1, M1, s2, h1f, nullptr);
    // GEMM2: (8192x4096 frag) x (4096x4096)^T -> h2lo/h2hi i8 planes (row-major)
    gemm_af<2><<<dim3((NB / 256) * (NH2 / 128)), dim3(512), 0, stream>>>(
        h1f, w2_i8, NB, NH2, NH1, b2, M2, nullptr, h2lo, h2hi);
    // head: 256 blocks (32 row-tiles x 8 K-chunks) -> part, then combine
    head_mfma<<<dim3(256), dim3(512), 0, stream>>>(h2lo, h2hi, wp_i8, part);
    comb_head<<<dim3(NB * NA / 256), dim3(256), 0, stream>>>(part, Ssum, bp, Mp, (float*)d_out);
}